// Round 4
// baseline (391.946 us; speedup 1.0000x reference)
//
#include <hip/hip_runtime.h>

// PatchGram, single launch, uniform 22.3 KiB LDS (7 blocks/CU):
//  block b -> (n = b>>1, layer = b&1), branch is block-uniform.
//  Layer 0 (C=512):  stage 18 KiB tile once, reduce 64 windows (k=8).
//  Layer 1 (C=1024): stage two 18 KiB half-tiles (512 ch each), reduce 32
//                    windows (k=16) per pass into fr rows [32h, 32h+32).
//  Then (shared): pooled rows B[dg] = sum_{dd<4} fr[4dg+dd] (pooling is
//  linear), out[c*16+dg] = 1/(36 k^2) * <fr[c], B[dg]>, float4 store.

#define N_SAMPLES 6272

typedef const __attribute__((address_space(1))) void* gas_ptr;
typedef __attribute__((address_space(3))) void* las_ptr;

__device__ __forceinline__ void load16_to_lds(const void* g, void* l) {
    __builtin_amdgcn_global_load_lds((gas_ptr)g, (las_ptr)l, 16, 0, 0);
}

struct Smem {
    float4 tile[1152];   // 18 KiB half/full tile (4608 floats)
    float4 fr4[64 * 3];  // fr rows padded to 12 floats
    float4 B4[16 * 3];
};                       // total 22272 B -> 7 blocks/CU

// Reduce a staged 1152-float4 tile. GSH = log2(lanes per window): 1 for k=8
// (64 windows), 2 for k=16 (32 windows). row_base offsets fr rows for the
// two-pass layer-1 path. Threads 0..127 active.
template <int GSH>
__device__ __forceinline__ void reduce_tile(Smem& sm, int t, int row_base) {
    if (t < 128) {
        const float4* __restrict__ tp = &sm.tile[t * 9];
        float acc[9];
#pragma unroll
        for (int p = 0; p < 9; ++p) acc[p] = 0.f;
#pragma unroll
        for (int j = 0; j < 9; ++j) {
            const float4 v = tp[j];
            acc[(4 * j + 0) % 9] += v.x;   // window offset 36t ≡ 0 (mod 9)
            acc[(4 * j + 1) % 9] += v.y;
            acc[(4 * j + 2) % 9] += v.z;
            acc[(4 * j + 3) % 9] += v.w;
        }
#pragma unroll
        for (int p = 0; p < 9; ++p) acc[p] += __shfl_xor(acc[p], 1);
        if (GSH == 2) {
#pragma unroll
            for (int p = 0; p < 9; ++p) acc[p] += __shfl_xor(acc[p], 2);
        }
        if ((t & ((1 << GSH) - 1)) == 0) {
            const int row = row_base + (t >> GSH);
            sm.fr4[row * 3 + 0] = make_float4(acc[0], acc[1], acc[2], acc[3]);
            sm.fr4[row * 3 + 1] = make_float4(acc[4], acc[5], acc[6], acc[7]);
            sm.fr4[row * 3 + 2] = make_float4(acc[8], 0.f, 0.f, 0.f);
        }
    }
}

__global__ __launch_bounds__(256, 6) void patchgram_kernel(
    const float* __restrict__ f0, const float* __restrict__ f1,
    float* __restrict__ out)
{
    __shared__ Smem sm;
    const int b     = blockIdx.x;
    const int t     = threadIdx.x;
    const int layer = b & 1;
    const int n     = b >> 1;

    if (!layer) {
        const float4* __restrict__ g = (const float4*)(f0 + (size_t)n * 4608);
        for (int i = t; i < 1152; i += 256) load16_to_lds(&g[i], &sm.tile[i]);
        __syncthreads();                       // drain vmcnt
        reduce_tile<1>(sm, t, 0);
        __syncthreads();
    } else {
        const float4* __restrict__ g = (const float4*)(f1 + (size_t)n * 9216);
#pragma unroll
        for (int h = 0; h < 2; ++h) {
            for (int i = t; i < 1152; i += 256)
                load16_to_lds(&g[h * 1152 + i], &sm.tile[i]);
            __syncthreads();                   // drain vmcnt
            reduce_tile<2>(sm, t, h * 32);
            __syncthreads();                   // tile reusable / fr visible
        }
    }

    // ---- pooled rows B[16][9] ----
    if (t < 144) {
        const int dg = t / 9;
        const int p  = t - dg * 9;
        const float* fr = (const float*)sm.fr4;
        ((float*)sm.B4)[dg * 12 + p] =
            fr[(4 * dg + 0) * 12 + p] + fr[(4 * dg + 1) * 12 + p] +
            fr[(4 * dg + 2) * 12 + p] + fr[(4 * dg + 3) * 12 + p];
    }
    __syncthreads();

    // ---- out[c][dg] = scale * <fr[c], B[dg]> ----
    const int c   = t >> 2;                    // 0..63
    const int dgq = t & 3;
    const float4 a0 = sm.fr4[c * 3 + 0];
    const float4 a1 = sm.fr4[c * 3 + 1];
    const float4 a2 = sm.fr4[c * 3 + 2];
    const float scale = layer ? (1.0f / (36.0f * 256.0f))
                              : (1.0f / (36.0f * 64.0f));

    float4 o4;
    float* op = (float*)&o4;
#pragma unroll
    for (int j = 0; j < 4; ++j) {
        const int d = dgq * 4 + j;
        const float4 b0 = sm.B4[d * 3 + 0];
        const float4 b1 = sm.B4[d * 3 + 1];
        const float4 b2 = sm.B4[d * 3 + 2];
        op[j] = (a0.x * b0.x + a0.y * b0.y + a0.z * b0.z + a0.w * b0.w
               + a1.x * b1.x + a1.y * b1.y + a1.z * b1.z + a1.w * b1.w
               + a2.x * b2.x) * scale;
    }
    float4* o = (float4*)(out + (size_t)n * 2048 + layer * 1024 + c * 16 + dgq * 4);
    *o = o4;
}

extern "C" void kernel_launch(void* const* d_in, const int* in_sizes, int n_in,
                              void* d_out, int out_size, void* d_ws, size_t ws_size,
                              hipStream_t stream) {
    const float* f0 = (const float*)d_in[0];   // [6272, 512, 3, 3]
    const float* f1 = (const float*)d_in[1];   // [6272, 1024, 3, 3]
    float* out = (float*)d_out;                // [6272, 2, 1024]
    patchgram_kernel<<<N_SAMPLES * 2, 256, 0, stream>>>(f0, f1, out);
}